// Round 2
// baseline (203.971 us; speedup 1.0000x reference)
//
#include <hip/hip_runtime.h>

#define N_NODES 5000
#define N_EDGES 160000
#define HID 64
#define BATCH 512

// ws layout (bytes):
//   0        deg        5000 i32   \
//   20000    cursor     5000 i32    } zeroed by prep (30000 words)
//   40000    xsum       5000 f32x4 /
//   120000   row_start  5000 i32
//   140000   sorted_src 160000 i32
//   780000   h1         5000x64 f32
//   2060000  h_part     5000x64 f32
//   3340000  t_part     512x64 f32
//   3471072  Wl1T(256) Wr1T(256) Wl2T(4096) Wr2T(4096) Wc1hT(4096)

// ---------- dispatch 1: zero counters + transpose weights + task MLP ----------
__global__ __launch_bounds__(64) void prep_kernel(
        const float* __restrict__ Wl1, const float* __restrict__ Wr1,
        const float* __restrict__ Wl2, const float* __restrict__ Wr2,
        const float* __restrict__ Wc1,
        const float* __restrict__ task_feat,
        const float* __restrict__ Wt1, const float* __restrict__ bt1,
        const float* __restrict__ Wt2, const float* __restrict__ bt2,
        const float* __restrict__ bc1,
        int* __restrict__ zero_region,      // deg+cursor+xsum, 30000 words
        float* __restrict__ Wl1T, float* __restrict__ Wr1T,
        float* __restrict__ Wl2T, float* __restrict__ Wr2T,
        float* __restrict__ Wc1hT, float* __restrict__ t_part) {
    int h = threadIdx.x;
    if (blockIdx.x < 64) {
        int k = blockIdx.x;
        // zero deg/cursor/xsum: 4096 threads x 8 slots
        int gtid = k * 64 + h;
#pragma unroll
        for (int r = 0; r < 8; r++) {
            int idx = r * 4096 + gtid;
            if (idx < 30000) zero_region[idx] = 0;
        }
        // transposes
        Wl2T[k * 64 + h]  = Wl2[h * 64 + k];
        Wr2T[k * 64 + h]  = Wr2[h * 64 + k];
        Wc1hT[k * 64 + h] = Wc1[h * 128 + k];
        if (k < 4) {
            Wl1T[k * 64 + h] = Wl1[h * 4 + k];
            Wr1T[k * 64 + h] = Wr1[h * 4 + k];
        }
    } else {
        // task MLP + t-half of classifier: one block per batch row
        int b = blockIdx.x - 64;
        __shared__ float s1[64], s2[64];
        float4 tf = ((const float4*)task_feat)[b];
        float4 w1 = ((const float4*)Wt1)[h];          // row h of Wt1 (64x4)
        float v = bt1[h] + tf.x * w1.x + tf.y * w1.y + tf.z * w1.z + tf.w * w1.w;
        s1[h] = fmaxf(v, 0.f);
        __syncthreads();
        const float4* w2r = (const float4*)(Wt2 + h * 64);   // row h of Wt2
        const float4* s1v = (const float4*)s1;
        float v2 = bt2[h];
#pragma unroll
        for (int q = 0; q < 16; q++) {
            float4 w = w2r[q]; float4 s = s1v[q];
            v2 += s.x * w.x + s.y * w.y + s.z * w.z + s.w * w.w;
        }
        s2[h] = v2;                                   // no relu on 2nd task layer
        __syncthreads();
        const float4* wc = (const float4*)(Wc1 + h * 128 + 64);  // t-half of row h
        const float4* s2v = (const float4*)s2;
        float p = bc1[h];
#pragma unroll
        for (int q = 0; q < 16; q++) {
            float4 w = wc[q]; float4 s = s2v[q];
            p += s.x * w.x + s.y * w.y + s.z * w.z + s.w * w.w;
        }
        t_part[b * 64 + h] = p;
    }
}

// ---------- dispatch 2: degree count + x-feature scatter (layer-1 aggregation) ----------
__global__ __launch_bounds__(256) void scatter_kernel(
        const int* __restrict__ ei, const float* __restrict__ x,
        int* __restrict__ deg, float* __restrict__ xsum) {
    int e = blockIdx.x * 256 + threadIdx.x;
    if (e >= N_EDGES) return;
    int src = ei[e];
    int dst = ei[N_EDGES + e];
    atomicAdd(&deg[dst], 1);
    float4 v = ((const float4*)x)[src];
    atomicAdd(&xsum[dst * 4 + 0], v.x);
    atomicAdd(&xsum[dst * 4 + 1], v.y);
    atomicAdd(&xsum[dst * 4 + 2], v.z);
    atomicAdd(&xsum[dst * 4 + 3], v.w);
}

// ---------- dispatch 3: block 0 = prefix scan of deg; blocks 1.. = layer 1 ----------
__global__ __launch_bounds__(256) void scan_layer1_kernel(
        const int* __restrict__ deg, const float* __restrict__ xsum,
        const float* __restrict__ x,
        const float* __restrict__ Wl1T, const float* __restrict__ bl1,
        const float* __restrict__ Wr1T,
        int* __restrict__ row_start, float* __restrict__ h1) {
    if (blockIdx.x == 0) {
        // exclusive scan of 5000 degrees: 256 threads x 20 values, shfl-based
        int t = threadIdx.x;
        int lane = t & 63, wave = t >> 6;
        int vals[20];
        int tot = 0;
        int base_i = t * 20;
#pragma unroll
        for (int j = 0; j < 20; j++) {
            int idx = base_i + j;
            int dv = (idx < N_NODES) ? deg[idx] : 0;
            vals[j] = tot;           // prefix within thread
            tot += dv;
        }
        int scan = tot;              // wave-inclusive scan of per-thread totals
#pragma unroll
        for (int off = 1; off < 64; off <<= 1) {
            int nb = __shfl_up(scan, off);
            if (lane >= off) scan += nb;
        }
        __shared__ int wtot[4];
        if (lane == 63) wtot[wave] = scan;
        __syncthreads();
        int wbase = 0;
        for (int w = 0; w < wave; w++) wbase += wtot[w];
        int tbase = wbase + scan - tot;   // exclusive base for this thread
#pragma unroll
        for (int j = 0; j < 20; j++) {
            int idx = base_i + j;
            if (idx < N_NODES) row_start[idx] = tbase + vals[j];
        }
    } else {
        // layer 1: 4 nodes per block, 64 lanes per node
        int lane = threadIdx.x & 63;
        int n = (blockIdx.x - 1) * 4 + (threadIdx.x >> 6);
        int d = deg[n];
        float inv = 1.f / fmaxf((float)d, 1.f);
        float4 xs = ((const float4*)xsum)[n];
        float4 xv = ((const float4*)x)[n];
        float v = bl1[lane]
                + (xs.x * inv) * Wl1T[0 * 64 + lane] + xv.x * Wr1T[0 * 64 + lane]
                + (xs.y * inv) * Wl1T[1 * 64 + lane] + xv.y * Wr1T[1 * 64 + lane]
                + (xs.z * inv) * Wl1T[2 * 64 + lane] + xv.z * Wr1T[2 * 64 + lane]
                + (xs.w * inv) * Wl1T[3 * 64 + lane] + xv.w * Wr1T[3 * 64 + lane];
        h1[n * 64 + lane] = fmaxf(v, 0.f);
    }
}

// ---------- dispatch 4: counting-sort edges by dst ----------
__global__ __launch_bounds__(256) void reorder_kernel(
        const int* __restrict__ ei, const int* __restrict__ row_start,
        int* __restrict__ cursor, int* __restrict__ sorted_src) {
    int e = blockIdx.x * 256 + threadIdx.x;
    if (e < N_EDGES) {
        int dst = ei[N_EDGES + e];
        int pos = atomicAdd(&cursor[dst], 1);
        sorted_src[row_start[dst] + pos] = ei[e];
    }
}

// ---------- dispatch 5: layer 2 fused with h_part = h2 @ Wc1[:, :64].T ----------
__global__ __launch_bounds__(256) void layer2_kernel(
        const float* __restrict__ h1, const int* __restrict__ deg,
        const int* __restrict__ row_start, const int* __restrict__ sorted_src,
        const float* __restrict__ Wl2T, const float* __restrict__ bl2,
        const float* __restrict__ Wr2T, const float* __restrict__ Wc1hT,
        float* __restrict__ h_part) {
    int h = threadIdx.x & 63;
    int grp = threadIdx.x >> 6;
    int n = blockIdx.x * 4 + grp;
    int d = deg[n];
    int s0 = row_start[n];
    float a0 = 0.f, a1 = 0.f, a2 = 0.f, a3 = 0.f;
    int j = 0;
    for (; j + 4 <= d; j += 4) {
        int e0 = sorted_src[s0 + j];
        int e1 = sorted_src[s0 + j + 1];
        int e2 = sorted_src[s0 + j + 2];
        int e3 = sorted_src[s0 + j + 3];
        a0 += h1[e0 * 64 + h];
        a1 += h1[e1 * 64 + h];
        a2 += h1[e2 * 64 + h];
        a3 += h1[e3 * 64 + h];
    }
    for (; j < d; j++) a0 += h1[sorted_src[s0 + j] * 64 + h];
    float m = (a0 + a1 + a2 + a3) / fmaxf((float)d, 1.f);

    __shared__ float shm[4][64], shh[4][64], shh2[4][64];
    shm[grp][h] = m;
    shh[grp][h] = h1[n * 64 + h];
    __syncthreads();
    float v = bl2[h];
#pragma unroll
    for (int k = 0; k < 64; k++)
        v += shm[grp][k] * Wl2T[k * 64 + h] + shh[grp][k] * Wr2T[k * 64 + h];
    shh2[grp][h] = fmaxf(v, 0.f);
    __syncthreads();
    float p = 0.f;
#pragma unroll
    for (int k = 0; k < 64; k++) p += shh2[grp][k] * Wc1hT[k * 64 + h];
    h_part[n * 64 + h] = p;
}

// ---------- dispatch 6: scores[b,n] = sum_h relu(hp[n,h]+tp[b,h])*Wc2[h] + bc2 ----------
__global__ __launch_bounds__(256) void scores_kernel(
        const float* __restrict__ h_part, const float* __restrict__ t_part,
        const float* __restrict__ Wc2, const float* __restrict__ bc2,
        float* __restrict__ out) {
    int tid = threadIdx.x;
    int n = blockIdx.x * 256 + tid;
    bool valid = n < N_NODES;
    int nn = valid ? n : (N_NODES - 1);
    float hr[64];
    const float4* hp = (const float4*)(h_part + nn * 64);
#pragma unroll
    for (int i = 0; i < 16; i++) {
        float4 v = hp[i];
        hr[4 * i + 0] = v.x; hr[4 * i + 1] = v.y;
        hr[4 * i + 2] = v.z; hr[4 * i + 3] = v.w;
    }
    float b2 = bc2[0];
    int b0 = blockIdx.y * 16;
    for (int bb = 0; bb < 16; bb++) {
        const float* tp = t_part + (b0 + bb) * 64;   // block-uniform address
        float acc = 0.f;
#pragma unroll
        for (int h = 0; h < 64; h++)
            acc = fmaf(fmaxf(hr[h] + tp[h], 0.f), Wc2[h], acc);
        if (valid) out[(b0 + bb) * N_NODES + n] = acc + b2;
    }
}

// ---------- launch ----------
extern "C" void kernel_launch(void* const* d_in, const int* in_sizes, int n_in,
                              void* d_out, int out_size, void* d_ws, size_t ws_size,
                              hipStream_t stream) {
    const float* x    = (const float*)d_in[0];
    const int*   ei   = (const int*)d_in[1];
    const float* task = (const float*)d_in[2];
    const float* Wl1  = (const float*)d_in[3];
    const float* bl1  = (const float*)d_in[4];
    const float* Wr1  = (const float*)d_in[5];
    const float* Wl2  = (const float*)d_in[6];
    const float* bl2  = (const float*)d_in[7];
    const float* Wr2  = (const float*)d_in[8];
    const float* Wt1  = (const float*)d_in[9];
    const float* bt1  = (const float*)d_in[10];
    const float* Wt2  = (const float*)d_in[11];
    const float* bt2  = (const float*)d_in[12];
    const float* Wc1  = (const float*)d_in[13];
    const float* bc1  = (const float*)d_in[14];
    const float* Wc2  = (const float*)d_in[15];
    const float* bc2  = (const float*)d_in[16];
    float* out = (float*)d_out;

    char* ws = (char*)d_ws;
    int*   deg        = (int*)(ws + 0);
    int*   cursor     = (int*)(ws + 20000);
    float* xsum       = (float*)(ws + 40000);
    int*   zero_reg   = (int*)(ws + 0);        // deg+cursor+xsum
    int*   row_start  = (int*)(ws + 120000);
    int*   sorted_src = (int*)(ws + 140000);
    float* h1         = (float*)(ws + 780000);
    float* h_part     = (float*)(ws + 2060000);
    float* t_part     = (float*)(ws + 3340000);
    float* Wl1T  = (float*)(ws + 3471072);
    float* Wr1T  = (float*)(ws + 3472096);
    float* Wl2T  = (float*)(ws + 3473120);
    float* Wr2T  = (float*)(ws + 3489504);
    float* Wc1hT = (float*)(ws + 3505888);

    prep_kernel<<<64 + BATCH, 64, 0, stream>>>(Wl1, Wr1, Wl2, Wr2, Wc1,
                                               task, Wt1, bt1, Wt2, bt2, bc1,
                                               zero_reg, Wl1T, Wr1T, Wl2T, Wr2T,
                                               Wc1hT, t_part);
    scatter_kernel<<<(N_EDGES + 255) / 256, 256, 0, stream>>>(ei, x, deg, xsum);
    scan_layer1_kernel<<<1 + N_NODES / 4, 256, 0, stream>>>(deg, xsum, x, Wl1T, bl1, Wr1T,
                                                            row_start, h1);
    reorder_kernel<<<(N_EDGES + 255) / 256, 256, 0, stream>>>(ei, row_start, cursor, sorted_src);
    layer2_kernel<<<N_NODES / 4, 256, 0, stream>>>(h1, deg, row_start, sorted_src,
                                                   Wl2T, bl2, Wr2T, Wc1hT, h_part);
    scores_kernel<<<dim3(20, 32), 256, 0, stream>>>(h_part, t_part, Wc2, bc2, out);
}

// Round 3
// 154.568 us; speedup vs baseline: 1.3196x; 1.3196x over previous
//
#include <hip/hip_runtime.h>

#define N_NODES 5000
#define N_EDGES 160000
#define HID 64
#define BATCH 512
#define EPB 2500      // edges per histogram/reorder block (64 blocks)
#define STRIDE 256    // fixed bucket stride (max deg ~32 avg, huge margin)

// ws layout (bytes):
//   0        blk_hist   64*5000 i32 (H: counts -> S1: block-exclusive offsets)
//   1280000  deg        5000 i32
//   1300000  sorted_src 5000*256 i32 (fixed-stride buckets)
//   6420000  h1         5000*64 f32
//   7700000  h_part     5000*64 f32
//   8980000  t_part     512*64 f32
//   9111072  Wl1T(256) Wr1T(256) Wl2T(4096) Wr2T(4096) Wc1hT(4096) f32

// ---------- dispatch 1: per-block edge histograms + weight transposes + task MLP ----------
__global__ __launch_bounds__(256) void prep_kernel(
        const int* __restrict__ ei,
        const float* __restrict__ Wl1, const float* __restrict__ Wr1,
        const float* __restrict__ Wl2, const float* __restrict__ Wr2,
        const float* __restrict__ Wc1,
        const float* __restrict__ task_feat,
        const float* __restrict__ Wt1, const float* __restrict__ bt1,
        const float* __restrict__ Wt2, const float* __restrict__ bt2,
        const float* __restrict__ bc1,
        int* __restrict__ blk_hist,
        float* __restrict__ Wl1T, float* __restrict__ Wr1T,
        float* __restrict__ Wl2T, float* __restrict__ Wr2T,
        float* __restrict__ Wc1hT, float* __restrict__ t_part) {
    int tid = threadIdx.x;
    int blk = blockIdx.x;
    __shared__ int hist[N_NODES];          // 20 KB, used only by blocks 0..63
    __shared__ float s1[4][64], s2[4][64]; // used only by task blocks

    if (blk < 64) {
        // LDS histogram of this block's 2500 edge destinations
        for (int i = tid; i < N_NODES; i += 256) hist[i] = 0;
        __syncthreads();
        int base = blk * EPB;
        for (int j = tid; j < EPB; j += 256)
            atomicAdd(&hist[ei[N_EDGES + base + j]], 1);
        __syncthreads();
        for (int i = tid; i < N_NODES; i += 256)
            blk_hist[blk * N_NODES + i] = hist[i];
    } else if (blk == 64) {
        for (int idx = tid; idx < 4096; idx += 256) {
            int k = idx >> 6, h = idx & 63;
            Wl2T[idx] = Wl2[h * 64 + k];
        }
    } else if (blk == 65) {
        for (int idx = tid; idx < 4096; idx += 256) {
            int k = idx >> 6, h = idx & 63;
            Wr2T[idx] = Wr2[h * 64 + k];
        }
    } else if (blk == 66) {
        for (int idx = tid; idx < 4096; idx += 256) {
            int k = idx >> 6, h = idx & 63;
            Wc1hT[idx] = Wc1[h * 128 + k];
        }
    } else if (blk == 67) {
        int k = tid >> 6, h = tid & 63;
        Wl1T[tid] = Wl1[h * 4 + k];
        Wr1T[tid] = Wr1[h * 4 + k];
    } else {
        // task MLP + t-half of classifier layer 1: 4 batch rows per block
        int grp = tid >> 6, h = tid & 63;
        int b = (blk - 68) * 4 + grp;
        float4 tf = ((const float4*)task_feat)[b];
        float4 w1 = ((const float4*)Wt1)[h];
        float v = bt1[h] + tf.x * w1.x + tf.y * w1.y + tf.z * w1.z + tf.w * w1.w;
        s1[grp][h] = fmaxf(v, 0.f);
        __syncthreads();
        const float4* w2r = (const float4*)(Wt2 + h * 64);
        const float4* s1v = (const float4*)s1[grp];
        float v2 = bt2[h];
#pragma unroll
        for (int q = 0; q < 16; q++) {
            float4 w = w2r[q]; float4 s = s1v[q];
            v2 += s.x * w.x + s.y * w.y + s.z * w.z + s.w * w.w;
        }
        s2[grp][h] = v2;   // no relu on 2nd task layer
        __syncthreads();
        const float4* wc  = (const float4*)(Wc1 + h * 128 + 64);
        const float4* s2v = (const float4*)s2[grp];
        float p = bc1[h];
#pragma unroll
        for (int q = 0; q < 16; q++) {
            float4 w = wc[q]; float4 s = s2v[q];
            p += s.x * w.x + s.y * w.y + s.z * w.z + s.w * w.w;
        }
        t_part[b * 64 + h] = p;
    }
}

// ---------- dispatch 2: per-node exclusive prefix over blocks (in-place) + deg ----------
__global__ __launch_bounds__(256) void offsets_kernel(int* __restrict__ blk_hist,
                                                      int* __restrict__ deg) {
    int n = blockIdx.x * 256 + threadIdx.x;
    if (n >= N_NODES) return;
    int run = 0;
#pragma unroll 8
    for (int b = 0; b < 64; b++) {
        int v = blk_hist[b * N_NODES + n];   // coalesced across threads
        blk_hist[b * N_NODES + n] = run;
        run += v;
    }
    deg[n] = run;
}

// ---------- dispatch 3: counting-sort edges into fixed-stride buckets (LDS cursors) ----------
__global__ __launch_bounds__(256) void reorder_kernel(
        const int* __restrict__ ei, const int* __restrict__ blk_hist,
        int* __restrict__ sorted_src) {
    __shared__ int cur[N_NODES];
    int tid = threadIdx.x;
    int blk = blockIdx.x;
    for (int i = tid; i < N_NODES; i += 256) cur[i] = 0;
    __syncthreads();
    int base = blk * EPB;
    const int* my_excl = blk_hist + blk * N_NODES;
    for (int j = tid; j < EPB; j += 256) {
        int src = ei[base + j];
        int dst = ei[N_EDGES + base + j];
        int local = atomicAdd(&cur[dst], 1);       // LDS atomic — fast
        sorted_src[dst * STRIDE + my_excl[dst] + local] = src;
    }
}

// ---------- dispatch 4: SAGE layer 1 (4 -> 64), bucket gather, 4 nodes/block ----------
__global__ __launch_bounds__(256) void layer1_kernel(
        const float* __restrict__ x, const int* __restrict__ deg,
        const int* __restrict__ sorted_src,
        const float* __restrict__ Wl1T, const float* __restrict__ bl1,
        const float* __restrict__ Wr1T, float* __restrict__ h1) {
    int lane = threadIdx.x & 63, grp = threadIdx.x >> 6;
    int n = blockIdx.x * 4 + grp;
    int d = deg[n];
    int f = lane & 3, g = lane >> 2;               // 16 neighbor slots x 4 features
    const int* bucket = sorted_src + n * STRIDE;
    float acc = 0.f;
    for (int j = g; j < d; j += 16) acc += x[bucket[j] * 4 + f];
    acc += __shfl_down(acc, 32);
    acc += __shfl_down(acc, 16);
    acc += __shfl_down(acc, 8);
    acc += __shfl_down(acc, 4);
    __shared__ float mean[4][4], xn[4][4];
    if (lane < 4) {
        mean[grp][lane] = acc / fmaxf((float)d, 1.f);  // lane == f here
        xn[grp][lane] = x[n * 4 + lane];
    }
    __syncthreads();
    float v = bl1[lane];
#pragma unroll
    for (int ff = 0; ff < 4; ff++)
        v += mean[grp][ff] * Wl1T[ff * 64 + lane] + xn[grp][ff] * Wr1T[ff * 64 + lane];
    h1[n * 64 + lane] = fmaxf(v, 0.f);
}

// ---------- dispatch 5: SAGE layer 2 (64 -> 64) fused with h_part = h2 @ Wc1[:,:64].T ----
__global__ __launch_bounds__(256) void layer2_kernel(
        const float* __restrict__ h1, const int* __restrict__ deg,
        const int* __restrict__ sorted_src,
        const float* __restrict__ Wl2T, const float* __restrict__ bl2,
        const float* __restrict__ Wr2T, const float* __restrict__ Wc1hT,
        float* __restrict__ h_part) {
    int h = threadIdx.x & 63, grp = threadIdx.x >> 6;
    int n = blockIdx.x * 4 + grp;
    int d = deg[n];
    const int* bucket = sorted_src + n * STRIDE;
    float a0 = 0.f, a1 = 0.f, a2 = 0.f, a3 = 0.f;
    int j = 0;
    for (; j + 4 <= d; j += 4) {
        int e0 = bucket[j], e1 = bucket[j + 1], e2 = bucket[j + 2], e3 = bucket[j + 3];
        a0 += h1[e0 * 64 + h];
        a1 += h1[e1 * 64 + h];
        a2 += h1[e2 * 64 + h];
        a3 += h1[e3 * 64 + h];
    }
    for (; j < d; j++) a0 += h1[bucket[j] * 64 + h];
    float m = (a0 + a1 + a2 + a3) / fmaxf((float)d, 1.f);

    __shared__ float shm[4][64], shh[4][64], shh2[4][64];
    shm[grp][h] = m;
    shh[grp][h] = h1[n * 64 + h];
    __syncthreads();
    float v = bl2[h];
#pragma unroll
    for (int k = 0; k < 64; k++)
        v += shm[grp][k] * Wl2T[k * 64 + h] + shh[grp][k] * Wr2T[k * 64 + h];
    shh2[grp][h] = fmaxf(v, 0.f);
    __syncthreads();
    float p = 0.f;
#pragma unroll
    for (int k = 0; k < 64; k++) p += shh2[grp][k] * Wc1hT[k * 64 + h];
    h_part[n * 64 + h] = p;
}

// ---------- dispatch 6: scores[b,n] = sum_h relu(hp[n,h]+tp[b,h])*Wc2[h] + bc2 ----------
__global__ __launch_bounds__(256) void scores_kernel(
        const float* __restrict__ h_part, const float* __restrict__ t_part,
        const float* __restrict__ Wc2, const float* __restrict__ bc2,
        float* __restrict__ out) {
    int tid = threadIdx.x;
    int n = blockIdx.x * 256 + tid;
    bool valid = n < N_NODES;
    int nn = valid ? n : (N_NODES - 1);
    float hr[64];
    const float4* hp = (const float4*)(h_part + nn * 64);
#pragma unroll
    for (int i = 0; i < 16; i++) {
        float4 v = hp[i];
        hr[4 * i + 0] = v.x; hr[4 * i + 1] = v.y;
        hr[4 * i + 2] = v.z; hr[4 * i + 3] = v.w;
    }
    float b2 = bc2[0];
    int b0 = blockIdx.y * 16;
    for (int bb = 0; bb < 16; bb++) {
        const float* tp = t_part + (b0 + bb) * 64;   // block-uniform address
        float acc = 0.f;
#pragma unroll
        for (int h = 0; h < 64; h++)
            acc = fmaf(fmaxf(hr[h] + tp[h], 0.f), Wc2[h], acc);
        if (valid) out[(b0 + bb) * N_NODES + n] = acc + b2;
    }
}

// ---------- launch ----------
extern "C" void kernel_launch(void* const* d_in, const int* in_sizes, int n_in,
                              void* d_out, int out_size, void* d_ws, size_t ws_size,
                              hipStream_t stream) {
    const float* x    = (const float*)d_in[0];
    const int*   ei   = (const int*)d_in[1];
    const float* task = (const float*)d_in[2];
    const float* Wl1  = (const float*)d_in[3];
    const float* bl1  = (const float*)d_in[4];
    const float* Wr1  = (const float*)d_in[5];
    const float* Wl2  = (const float*)d_in[6];
    const float* bl2  = (const float*)d_in[7];
    const float* Wr2  = (const float*)d_in[8];
    const float* Wt1  = (const float*)d_in[9];
    const float* bt1  = (const float*)d_in[10];
    const float* Wt2  = (const float*)d_in[11];
    const float* bt2  = (const float*)d_in[12];
    const float* Wc1  = (const float*)d_in[13];
    const float* bc1  = (const float*)d_in[14];
    const float* Wc2  = (const float*)d_in[15];
    const float* bc2  = (const float*)d_in[16];
    float* out = (float*)d_out;

    char* ws = (char*)d_ws;
    int*   blk_hist   = (int*)(ws + 0);
    int*   deg        = (int*)(ws + 1280000);
    int*   sorted_src = (int*)(ws + 1300000);
    float* h1         = (float*)(ws + 6420000);
    float* h_part     = (float*)(ws + 7700000);
    float* t_part     = (float*)(ws + 8980000);
    float* Wl1T  = (float*)(ws + 9111072);
    float* Wr1T  = (float*)(ws + 9112096);
    float* Wl2T  = (float*)(ws + 9113120);
    float* Wr2T  = (float*)(ws + 9129504);
    float* Wc1hT = (float*)(ws + 9145888);

    prep_kernel<<<68 + BATCH / 4, 256, 0, stream>>>(ei, Wl1, Wr1, Wl2, Wr2, Wc1,
                                                    task, Wt1, bt1, Wt2, bt2, bc1,
                                                    blk_hist, Wl1T, Wr1T, Wl2T, Wr2T,
                                                    Wc1hT, t_part);
    offsets_kernel<<<(N_NODES + 255) / 256, 256, 0, stream>>>(blk_hist, deg);
    reorder_kernel<<<64, 256, 0, stream>>>(ei, blk_hist, sorted_src);
    layer1_kernel<<<N_NODES / 4, 256, 0, stream>>>(x, deg, sorted_src, Wl1T, bl1, Wr1T, h1);
    layer2_kernel<<<N_NODES / 4, 256, 0, stream>>>(h1, deg, sorted_src, Wl2T, bl2, Wr2T,
                                                   Wc1hT, h_part);
    scores_kernel<<<dim3(20, 32), 256, 0, stream>>>(h_part, t_part, Wc2, bc2, out);
}